// Round 7
// baseline (678.973 us; speedup 1.0000x reference)
//
#include <hip/hip_runtime.h>
#include <math.h>

// Problem constants
#define TT 32
#define BB 128
#define DD 256
#define HH 768
#define MAXP 8

// 8 rowgroups (16 rows) x 12 col-blocks (64 cols); 256 thr = 4 waves = 4 col-tiles
#define RG   8
#define RPG  16
#define CB   12
#define CS   64
#define NTH  256
#define NCH  24    // K chunks of 32

#define OFF_LAST  ((size_t)TT * BB * HH)
#define OFF_PCOST (OFF_LAST + (size_t)BB * HH)
#define OFF_STEPS (OFF_PCOST + BB)

#define ASCOPE __HIP_MEMORY_SCOPE_AGENT

// Self-validating exchange: per (group,parity) buffer = 16 rows x 96 col-octets
// x 3 ull. Each ull = 3 bf16 payload + 16-bit phase seq in bits [48,64).
// Aligned 8B stores/loads are single-copy atomic -> no tearing; per-word seq
// makes store order irrelevant -> no drain / no flag / no fence on the path.
#define BUF_ULL (RPG * 96 * 3)   // 4608 ull = 36 KB

typedef __attribute__((ext_vector_type(8))) short s16x8;
typedef __attribute__((ext_vector_type(4))) float f32x4;
typedef unsigned long long ull;

static __device__ __forceinline__ unsigned short f2bf(float f) {
    unsigned u = __float_as_uint(f);
    u = (u + 0x7fffu + ((u >> 16) & 1u)) >> 16;   // RNE
    return (unsigned short)u;
}
static __device__ __forceinline__ float bf2f(unsigned short h) {
    return __uint_as_float(((unsigned)h) << 16);
}

__launch_bounds__(NTH, 1)
__global__ void act_kernel(const float* __restrict__ x,
                           const float* __restrict__ Wih,
                           const float* __restrict__ Whh,
                           const float* __restrict__ bih,
                           const float* __restrict__ bhh,
                           const float* __restrict__ wpv,
                           const float* __restrict__ bp,
                           float* __restrict__ out,
                           unsigned* __restrict__ progress,
                           ull* __restrict__ hxe)
{
    const int tid  = threadIdx.x;
    const int g    = blockIdx.x & 7;     // rowgroup
    const int ib   = blockIdx.x >> 3;    // col-block [0,12)
    const int r0   = g * RPG;
    const int c0   = ib * CS;
    const int CT   = tid >> 6;           // wave = col-tile [0,4)
    const int lane = tid & 63;
    const int am   = lane & 15;          // this thread's batch row (A-row / C-col)
    const int aq   = lane >> 4;

    // LDS ~69 KB -> 1 block/CU
    __shared__ s16x8 A_s[NCH * 64];          // hx A-frags (24.5 KB)
    __shared__ s16x8 WB_s[4 * 8 * 64];       // Wih B-frags (32 KB)
    __shared__ s16x8 xA_s[8 * 64];           // x_t A-frags (8 KB)
    __shared__ unsigned short hxn_s[RPG][72];
    __shared__ float zw_s[4][20];
    __shared__ float bias_s[CS], wflag_s[CS];

    // ---- init: Whh B-frags -> permanent VGPRs (96) ----
    s16x8 Breg[NCH];
    {
        const float* wr = Whh + (size_t)(c0 + CT*16 + am) * HH + aq*8;
        for (int ch = 0; ch < NCH; ++ch) {
            float4 a0 = *(const float4*)(wr + ch*32);
            float4 a1 = *(const float4*)(wr + ch*32 + 4);
            union { s16x8 v; unsigned short e[8]; } u;
            u.e[0]=f2bf(a0.x); u.e[1]=f2bf(a0.y); u.e[2]=f2bf(a0.z); u.e[3]=f2bf(a0.w);
            u.e[4]=f2bf(a1.x); u.e[5]=f2bf(a1.y); u.e[6]=f2bf(a1.z); u.e[7]=f2bf(a1.w);
            Breg[ch] = u.v;
        }
    }
    for (int ch = 0; ch < 8; ++ch) {   // Wih B-frags (row stride 257 -> scalar, init-only)
        const float* wr = Wih + (size_t)(c0 + CT*16 + am) * (DD+1) + ch*32 + aq*8;
        union { s16x8 v; unsigned short e[8]; } u;
        #pragma unroll
        for (int j = 0; j < 8; ++j) u.e[j] = f2bf(wr[j]);
        WB_s[(CT*8 + ch)*64 + lane] = u.v;
    }
    if (tid < CS) {
        bias_s[tid]  = bih[c0+tid] + bhh[c0+tid];
        wflag_s[tid] = Wih[(size_t)(c0+tid)*(DD+1) + DD];
    }
    const float bpr = bp[0];
    float wpreg[48];                    // w_p for this thread's 48 columns
    #pragma unroll
    for (int j = 0; j < 6; ++j)
        #pragma unroll
        for (int i = 0; i < 8; ++i)
            wpreg[j*8+i] = wpv[(j*4 + CT)*32 + aq*8 + i];
    {
        s16x8 z8 = {0,0,0,0,0,0,0,0};
        #pragma unroll
        for (int j = 0; j < 6; ++j) A_s[j*NTH + tid] = z8;   // hx0 = 0
    }

    float ahx[48];
    unsigned it = 1;   // monotone phase counter; seq = it&0xffff; buffers memset to 0
    // per-thread replicated ponder state for row am (bitwise-identical everywhere)
    float ahR = 0.f, spcR = 0.f, scR = 0.f, pcR = 0.f;
    int   actR = 1;

    // writer octet mapping (tid < 128): row wr_r, octet wr_o within own 64 cols
    const int wr_r = tid >> 3;
    const int wr_o = tid & 7;
    // reader fan-in base indices for (row am, 6 col-octets)
    // octet s(j) = (j*4+CT)*4 + aq ; word base = (am*96 + s)*3

    // prefetch x(0)
    float4 xp0, xp1, xp2, xp3;
    {
        const float* xb = x + (size_t)(r0 + am)*DD;
        xp0 = *(const float4*)(xb + CT*32 + aq*8);
        xp1 = *(const float4*)(xb + CT*32 + aq*8 + 4);
        xp2 = *(const float4*)(xb + (4+CT)*32 + aq*8);
        xp3 = *(const float4*)(xb + (4+CT)*32 + aq*8 + 4);
    }
    __syncthreads();   // WB_s / bias_s ready

    for (int t = 0; t < TT; ++t) {
        // ---- pack prefetched x_t into A-frags ----
        {
            union { s16x8 v; unsigned short e[8]; } u;
            u.e[0]=f2bf(xp0.x); u.e[1]=f2bf(xp0.y); u.e[2]=f2bf(xp0.z); u.e[3]=f2bf(xp0.w);
            u.e[4]=f2bf(xp1.x); u.e[5]=f2bf(xp1.y); u.e[6]=f2bf(xp1.z); u.e[7]=f2bf(xp1.w);
            xA_s[tid] = u.v;
            u.e[0]=f2bf(xp2.x); u.e[1]=f2bf(xp2.y); u.e[2]=f2bf(xp2.z); u.e[3]=f2bf(xp2.w);
            u.e[4]=f2bf(xp3.x); u.e[5]=f2bf(xp3.y); u.e[6]=f2bf(xp3.z); u.e[7]=f2bf(xp3.w);
            xA_s[NTH + tid] = u.v;
        }
        ahR = 0.f; spcR = 0.f; scR = 0.f; actR = 1;
        #pragma unroll
        for (int q = 0; q < 48; ++q) ahx[q] = 0.f;
        __syncthreads();

        // ---- xi = x_t @ Wih^T + bias (2 independent MFMA chains) ----
        f32x4 xi;
        {
            f32x4 a0 = {0.f,0.f,0.f,0.f}, a1 = {0.f,0.f,0.f,0.f};
            #pragma unroll
            for (int ch = 0; ch < 8; ch += 2) {
                a0 = __builtin_amdgcn_mfma_f32_16x16x32_bf16(
                        xA_s[ch*64 + lane],     WB_s[(CT*8 + ch)*64 + lane],     a0, 0,0,0);
                a1 = __builtin_amdgcn_mfma_f32_16x16x32_bf16(
                        xA_s[(ch+1)*64 + lane], WB_s[(CT*8 + ch+1)*64 + lane],   a1, 0,0,0);
            }
            const float bs = bias_s[CT*16 + am];
            xi[0]=a0[0]+a1[0]+bs; xi[1]=a0[1]+a1[1]+bs;
            xi[2]=a0[2]+a1[2]+bs; xi[3]=a0[3]+a1[3]+bs;
        }
        // prefetch x(t+1) (in flight across the ponder loop)
        if (t + 1 < TT) {
            const float* xb = x + ((size_t)(t+1)*BB + r0 + am)*DD;
            xp0 = *(const float4*)(xb + CT*32 + aq*8);
            xp1 = *(const float4*)(xb + CT*32 + aq*8 + 4);
            xp2 = *(const float4*)(xb + (4+CT)*32 + aq*8);
            xp3 = *(const float4*)(xb + (4+CT)*32 + aq*8 + 4);
        }

        // ---- ponder loop ----
        int pk = 0;
        for (;;) {
            const unsigned cur = it;
            const ull sq = (ull)(cur & 0xffffu);
            ull* exch = hxe + (size_t)(g*2 + (cur & 1u)) * BUF_ULL;

            // matvec: 2 independent MFMA chains over K
            f32x4 a0 = xi, a1 = {0.f,0.f,0.f,0.f};
            #pragma unroll
            for (int ch = 0; ch < NCH; ch += 2) {
                a0 = __builtin_amdgcn_mfma_f32_16x16x32_bf16(A_s[ch*64 + lane],     Breg[ch],   a0, 0,0,0);
                a1 = __builtin_amdgcn_mfma_f32_16x16x32_bf16(A_s[(ch+1)*64 + lane], Breg[ch+1], a1, 0,0,0);
            }
            const float fl = pk ? wflag_s[CT*16 + am] : 0.f;
            #pragma unroll
            for (int r = 0; r < 4; ++r)
                hxn_s[aq*4 + r][CT*16 + am] = f2bf(tanhf(a0[r] + a1[r] + fl));
            __syncthreads();   // S1: hxn_s ready

            // anti-overrun gate (off critical path in steady state): before
            // re-using parity (cur&1), all blocks must have finished reading
            // phase cur-2. Each wave polls independently (no extra sync).
            if (cur > 2) {
                const unsigned tgt = cur - 2;
                const unsigned* pa = &progress[g*16 + (lane % 12)];
                unsigned v;
                do { v = __hip_atomic_load(pa, __ATOMIC_RELAXED, ASCOPE); }
                while (!__all((int)(v >= tgt)));
            }

            // publish own 64-col slice: 128 threads x 1 octet (3 seq-tagged ull).
            // Relaxed stores, NO drain, NO flag — readers self-validate per word.
            if (tid < 128) {
                const ull A = *(const ull*)&hxn_s[wr_r][wr_o*8];
                const ull B = *(const ull*)&hxn_s[wr_r][wr_o*8 + 4];
                const ull u0 = (A & 0x0000FFFFFFFFFFFFULL) | (sq << 48);
                const ull u1 = ((A >> 48) | ((B & 0xFFFFFFFFULL) << 16)) | (sq << 48);
                const ull u2 = (B >> 32) | (sq << 48);
                ull* dst = exch + (size_t)(wr_r*96 + ib*8 + wr_o)*3;
                __hip_atomic_store(dst,     u0, __ATOMIC_RELAXED, ASCOPE);
                __hip_atomic_store(dst + 1, u1, __ATOMIC_RELAXED, ASCOPE);
                __hip_atomic_store(dst + 2, u2, __ATOMIC_RELAXED, ASCOPE);
            }

            // fan-in with per-word seq validation (retry until all 18 current)
            ull u0[6], u1[6], u2[6];
            {
                const ull* bptr[6];
                #pragma unroll
                for (int j = 0; j < 6; ++j)
                    bptr[j] = exch + (size_t)(am*96 + ((j*4 + CT)*4 + aq))*3;
                int okall;
                do {
                    okall = 1;
                    #pragma unroll
                    for (int j = 0; j < 6; ++j) {
                        u0[j] = __hip_atomic_load(bptr[j],     __ATOMIC_RELAXED, ASCOPE);
                        u1[j] = __hip_atomic_load(bptr[j] + 1, __ATOMIC_RELAXED, ASCOPE);
                        u2[j] = __hip_atomic_load(bptr[j] + 2, __ATOMIC_RELAXED, ASCOPE);
                    }
                    #pragma unroll
                    for (int j = 0; j < 6; ++j)
                        okall &= ((u0[j] >> 48) == sq) & ((u1[j] >> 48) == sq)
                               & ((u2[j] >> 48) == sq);
                } while (!__all(okall));
            }

            // unpack 48 bf16 (row am, own 48 cols)
            unsigned short d[48];
            #pragma unroll
            for (int j = 0; j < 6; ++j) {
                d[j*8+0] = (unsigned short)u0[j];
                d[j*8+1] = (unsigned short)(u0[j] >> 16);
                d[j*8+2] = (unsigned short)(u0[j] >> 32);
                d[j*8+3] = (unsigned short)u1[j];
                d[j*8+4] = (unsigned short)(u1[j] >> 16);
                d[j*8+5] = (unsigned short)(u1[j] >> 32);
                d[j*8+6] = (unsigned short)u2[j];
                d[j*8+7] = (unsigned short)(u2[j] >> 16);
            }

            // z for row am: per-thread partial (fixed order) -> butterfly -> cross-wave
            float zp = 0.f;
            #pragma unroll
            for (int q = 0; q < 48; ++q) zp += bf2f(d[q]) * wpreg[q];
            zp += __shfl_xor(zp, 16);
            zp += __shfl_xor(zp, 32);
            if (lane < 16) zw_s[CT][lane] = zp;
            __syncthreads();   // S4: zw ready; all waves validated
            if (tid == 0)      // block done reading this parity buffer
                __hip_atomic_store(&progress[g*16 + ib], cur, __ATOMIC_RELAXED, ASCOPE);
            const float z = ((zw_s[0][am] + zw_s[1][am]) + zw_s[2][am]) + zw_s[3][am];

            // replicated scalar ponder update (row am; identical in every thread/block)
            float w1 = 0.f;
            if (actR) {
                const float h = 1.f / (1.f + expf(-(z + bpr)));
                spcR = -ahR;
                const float ah2 = ahR + h;
                const float p = h - fmaxf(ah2 - 1.f, 0.f);
                w1 = 1.f + p;
                scR += 1.f;
                ahR = ah2;
                actR = (ah2 < 0.99f) ? 1 : 0;   // 1-EPS == 0.99f exactly
            }

            // accum_hx + hx_i freeze (w1!=0 <=> row active this iteration)
            if (w1 != 0.f) {
                #pragma unroll
                for (int j = 0; j < 6; ++j) {
                    union { s16x8 v; unsigned short e[8]; } cv;
                    #pragma unroll
                    for (int i = 0; i < 8; ++i) {
                        ahx[j*8 + i] += w1 * bf2f(d[j*8 + i]);
                        cv.e[i] = d[j*8 + i];
                    }
                    A_s[j*NTH + tid] = cv.v;
                }
            }
            const int nact = (int)__popcll(__ballot(actR != 0) & 0xFFFFull);
            ++it; ++pk;
            __syncthreads();   // S5: A_s ready for next matvec
            if (nact == 0 || pk == MAXP) break;
        }

        // ---- finalize t (state replicated -> no extra sync) ----
        pcR += spcR;
        const float inv = 1.f / scR;
        if (ib == 0 && tid < 16) out[OFF_STEPS + (size_t)t*BB + r0 + tid] = scR;
        #pragma unroll
        for (int j = 0; j < 6; ++j) {
            float o[8];
            #pragma unroll
            for (int i = 0; i < 8; ++i) o[i] = ahx[j*8 + i] * inv;
            union { s16x8 v; unsigned short e[8]; } u;
            #pragma unroll
            for (int i = 0; i < 8; ++i) u.e[i] = f2bf(o[i]);
            A_s[j*NTH + tid] = u.v;   // hx for next t (replicated in every block)
            if (ib == 0) {
                float* op = out + ((size_t)t*BB + r0 + am)*HH + (j*4 + CT)*32 + aq*8;
                *(float4*)op       = make_float4(o[0], o[1], o[2], o[3]);
                *(float4*)(op + 4) = make_float4(o[4], o[5], o[6], o[7]);
                if (t == TT-1) {
                    float* lp = out + OFF_LAST + (size_t)(r0 + am)*HH + (j*4 + CT)*32 + aq*8;
                    *(float4*)lp       = make_float4(o[0], o[1], o[2], o[3]);
                    *(float4*)(lp + 4) = make_float4(o[4], o[5], o[6], o[7]);
                }
            }
        }
        __syncthreads();
    }
    if (ib == 0 && tid < 16) out[OFF_PCOST + r0 + tid] = pcR;
}

extern "C" void kernel_launch(void* const* d_in, const int* in_sizes, int n_in,
                              void* d_out, int out_size, void* d_ws, size_t ws_size,
                              hipStream_t stream) {
    const float* x   = (const float*)d_in[0];
    const float* Wih = (const float*)d_in[1];
    const float* Whh = (const float*)d_in[2];
    const float* bih = (const float*)d_in[3];
    const float* bhh = (const float*)d_in[4];
    const float* wpv = (const float*)d_in[5];
    const float* bp  = (const float*)d_in[6];
    float* out = (float*)d_out;

    // ws: [0,4096) progress counters; [4096, +576 KB) seq-tagged hx exchange
    // (8 groups x 2 parities x 36 KB). ALL of it memset each launch: seq=0
    // never matches a live phase -> no stale-replay ABA.
    unsigned* progress = (unsigned*)d_ws;
    ull*      hxe      = (ull*)((char*)d_ws + 4096);
    const size_t clr = 4096 + (size_t)RG * 2 * BUF_ULL * 8;

    hipMemsetAsync(d_ws, 0, clr, stream);
    act_kernel<<<dim3(RG*CB), dim3(NTH), 0, stream>>>(
        x, Wih, Whh, bih, bhh, wpv, bp, out, progress, hxe);
}